// Round 1
// 264.712 us; speedup vs baseline: 1.0460x; 1.0460x over previous
//
#include <hip/hip_runtime.h>
#include <hip/hip_bf16.h>

typedef __attribute__((ext_vector_type(8))) short sh8;
typedef __attribute__((ext_vector_type(4))) short sh4;
typedef __attribute__((ext_vector_type(4))) float f4v;
typedef __attribute__((ext_vector_type(4))) unsigned u4v;
typedef __attribute__((ext_vector_type(2))) unsigned u2v;

#define SCALE_Q 0.1803368801f   // 0.125 * log2(e): folds softmax scale AND exp->exp2

__device__ __forceinline__ short f2bf(float f) {
    unsigned u = __builtin_bit_cast(unsigned, f);
    u += 0x7fffu + ((u >> 16) & 1u);   // RNE
    return (short)(u >> 16);
}

#if __has_builtin(__builtin_amdgcn_cvt_pk_bf16_f32)
__device__ __forceinline__ unsigned pk_bf16(float a, float b) {
    return __builtin_bit_cast(unsigned, __builtin_amdgcn_cvt_pk_bf16_f32(a, b));
}
#else
__device__ __forceinline__ unsigned pk_bf16(float a, float b) {
    return (unsigned)(unsigned short)f2bf(a) | ((unsigned)(unsigned short)f2bf(b) << 16);
}
#endif

#if __has_builtin(__builtin_amdgcn_exp2f)
#define EXP2(x) __builtin_amdgcn_exp2f(x)
#else
#define EXP2(x) exp2f(x)
#endif

__device__ __forceinline__ void glds16(const short* g, short* l) {
    __builtin_amdgcn_global_load_lds(
        (const __attribute__((address_space(1))) void*)g,
        (__attribute__((address_space(3))) void*)l, 16, 0, 0);
}

// ---------------- pack: fp32 -> bf16 conversions + weight fusion ----------------
// vec4 regions: x->xb | Wq->Wqkb(scaled) | Wk->Wqkb+1M | Wv->Wvb | Wo->Wob | biases
__global__ __launch_bounds__(256)
void pack_all(const float* __restrict__ x,  const float* __restrict__ Wq,
              const float* __restrict__ Wk, const float* __restrict__ Wv,
              const float* __restrict__ Wo, const float* __restrict__ bq,
              const float* __restrict__ bk, const float* __restrict__ bv,
              short* __restrict__ xb, short* __restrict__ Wqkb,
              short* __restrict__ Wvb, short* __restrict__ Wob,
              float* __restrict__ bqk, float* __restrict__ bvf)
{
    const long idx = (long)blockIdx.x * 256 + threadIdx.x;
    if (idx >= 2752896) return;
    const float* src; short* dst; float sc = 1.0f; long off;
    if (idx < 2097152)       { off = idx;           src = x;  dst = xb; }
    else if (idx < 2359296)  { off = idx - 2097152; src = Wq; dst = Wqkb;           sc = SCALE_Q; }
    else if (idx < 2424832)  { off = idx - 2359296; src = Wk; dst = Wqkb + 1048576; }
    else if (idx < 2490368)  { off = idx - 2424832; src = Wv; dst = Wvb; }
    else if (idx < 2752512)  { off = idx - 2490368; src = Wo; dst = Wob; }
    else {
        long j = idx - 2752512;  // 0..383
        const float* bs; float* bd; float s2 = 1.0f;
        if (j < 256)      { bs = bq + j * 4;         bd = bqk + j * 4;          s2 = SCALE_Q; }
        else if (j < 320) { bs = bk + (j - 256) * 4; bd = bqk + 1024 + (j - 256) * 4; }
        else              { bs = bv + (j - 320) * 4; bd = bvf + (j - 320) * 4; }
        f4v v = *reinterpret_cast<const f4v*>(bs);
        f4v o = { v[0] * s2, v[1] * s2, v[2] * s2, v[3] * s2 };
        *reinterpret_cast<f4v*>(bd) = o;
        return;
    }
    f4v v = *reinterpret_cast<const f4v*>(src + off * 4);
    sh4 o; o[0] = f2bf(v[0] * sc); o[1] = f2bf(v[1] * sc);
    o[2] = f2bf(v[2] * sc); o[3] = f2bf(v[3] * sc);
    *reinterpret_cast<sh4*>(dst + off * 4) = o;
}

// ---------------- fused projection: QK GEMM + V-transposed GEMM, one grid ----------------
// Blocks 0..639:   QKb[8192][1280] = xb[8192][1024] · Wqkb[1280][1024]^T + bqk (col bias)
// Blocks 640..767: Vt [256][8192]  = Wvb[256][1024] · xb[8192][1024]^T  + bvf (row bias)
//   (swapped operands make the token axis the store-lane axis -> coalesced Vt, no scatter)
// Grid 768 = 3 x 256: zero tail. K=1024, 128x128 tiles, m97-style glds staging.
__global__ __launch_bounds__(256)
void proj_fused(const short* __restrict__ xb, const short* __restrict__ Wqkb,
                const float* __restrict__ bqk, short* __restrict__ QKb,
                const short* __restrict__ Wvb, const float* __restrict__ bvf,
                short* __restrict__ Vt)
{
    constexpr int K = 1024;
    __shared__ __attribute__((aligned(16))) short As[128 * 32];
    __shared__ __attribute__((aligned(16))) short Bs[128 * 32];

    const int t = threadIdx.x, lane = t & 63, w = t >> 6;
    const int lr = lane & 15, quad = lane >> 4;
    const int wm = (w >> 1) * 64, wn = (w & 1) * 64;
    const int sr = lane >> 2, sc = lane & 3;

    const int id = blockIdx.x;
    const short *A, *B; const float* bias; short* C;
    int m0, n0, N; bool brow;
    if (id < 640) {
        A = xb;  B = Wqkb; bias = bqk; C = QKb; N = 1280;
        m0 = (id / 10) * 128; n0 = (id % 10) * 128; brow = false;
    } else {
        const int v = id - 640;
        A = Wvb; B = xb;   bias = bvf; C = Vt;  N = 8192;
        m0 = (v >> 6) * 128; n0 = (v & 63) * 128; brow = true;
    }

    f4v acc[4][4] = {};

    for (int kb = 0; kb < K; kb += 32) {
#pragma unroll
        for (int p = 0; p < 2; ++p) {
            const int s = 2 * w + p;
            const int r = s * 16 + sr;
            const int g = sc ^ ((r >> 1) & 3);
            glds16(A + (size_t)(m0 + r) * K + kb + g * 8, &As[s * 512]);
            glds16(B + (size_t)(n0 + r) * K + kb + g * 8, &Bs[s * 512]);
        }
        __syncthreads();
        sh8 af[4], bfr[4];
#pragma unroll
        for (int i = 0; i < 4; ++i) {
            const int ra = wm + i * 16 + lr;
            af[i] = *reinterpret_cast<const sh8*>(&As[ra * 32 + ((quad ^ ((ra >> 1) & 3)) << 3)]);
            const int rb = wn + i * 16 + lr;
            bfr[i] = *reinterpret_cast<const sh8*>(&Bs[rb * 32 + ((quad ^ ((rb >> 1) & 3)) << 3)]);
        }
#pragma unroll
        for (int mi = 0; mi < 4; ++mi)
#pragma unroll
            for (int ni = 0; ni < 4; ++ni)
                acc[mi][ni] = __builtin_amdgcn_mfma_f32_16x16x32_bf16(af[mi], bfr[ni], acc[mi][ni], 0, 0, 0);
        __syncthreads();
    }

#pragma unroll
    for (int mi = 0; mi < 4; ++mi) {
        const int row = m0 + wm + mi * 16 + quad * 4;
        f4v br4 = {};
        if (brow) br4 = *reinterpret_cast<const f4v*>(&bias[row]);
#pragma unroll
        for (int ni = 0; ni < 4; ++ni) {
            const int col = n0 + wn + ni * 16 + lr;
            const float bc = brow ? 0.f : bias[col];
#pragma unroll
            for (int i = 0; i < 4; ++i) {
                const float v = acc[mi][ni][i] + (brow ? br4[i] : bc);
                C[(size_t)(row + i) * N + col] = f2bf(v);
            }
        }
    }
}

// ---------------- O-projection GEMM: out[M,N] = A[M,K] · W[N,K]^T + bias (fp32 out) ----------------
__global__ __launch_bounds__(256)
void gemm_out(const short* __restrict__ A, const short* __restrict__ B,
              const float* __restrict__ bias, float* __restrict__ Cv,
              int M, int N, int K)
{
    __shared__ __attribute__((aligned(16))) short As[128 * 32];
    __shared__ __attribute__((aligned(16))) short Bs[128 * 32];

    const int t = threadIdx.x, lane = t & 63, w = t >> 6;
    const int lr = lane & 15, quad = lane >> 4;
    const int m0 = blockIdx.y * 128, n0 = blockIdx.x * 128;
    const int wm = (w >> 1) * 64, wn = (w & 1) * 64;
    const int sr = lane >> 2, sc = lane & 3;

    f4v acc[4][4] = {};

    for (int kb = 0; kb < K; kb += 32) {
#pragma unroll
        for (int p = 0; p < 2; ++p) {
            const int s = 2 * w + p;
            const int r = s * 16 + sr;
            const int g = sc ^ ((r >> 1) & 3);
            glds16(A + (size_t)(m0 + r) * K + kb + g * 8, &As[s * 512]);
            glds16(B + (size_t)(n0 + r) * K + kb + g * 8, &Bs[s * 512]);
        }
        __syncthreads();
        sh8 af[4], bfr[4];
#pragma unroll
        for (int i = 0; i < 4; ++i) {
            const int ra = wm + i * 16 + lr;
            af[i] = *reinterpret_cast<const sh8*>(&As[ra * 32 + ((quad ^ ((ra >> 1) & 3)) << 3)]);
            const int rb = wn + i * 16 + lr;
            bfr[i] = *reinterpret_cast<const sh8*>(&Bs[rb * 32 + ((quad ^ ((rb >> 1) & 3)) << 3)]);
        }
#pragma unroll
        for (int mi = 0; mi < 4; ++mi)
#pragma unroll
            for (int ni = 0; ni < 4; ++ni)
                acc[mi][ni] = __builtin_amdgcn_mfma_f32_16x16x32_bf16(af[mi], bfr[ni], acc[mi][ni], 0, 0, 0);
        __syncthreads();
    }

#pragma unroll
    for (int ni = 0; ni < 4; ++ni) {
        const int col = n0 + wn + ni * 16 + lr;
        const float bv = bias[col];
#pragma unroll
        for (int mi = 0; mi < 4; ++mi) {
            const int row = m0 + wm + mi * 16 + quad * 4;
#pragma unroll
            for (int i = 0; i < 4; ++i)
                Cv[(size_t)(row + i) * N + col] = acc[mi][ni][i] + bv;
        }
    }
}

// ---------------- flash attention: S^T/O^T formulation, P in registers ----------------
// QKb [8192][1280]: Q cols 0..1023 (pre-scaled by 0.125*log2e), K cols 1024..1279.
// Vt [256][8192]: V^T, token-contiguous rows.
// NEW (this round): 64-key tiles, double-buffered LDS (2 x 16KB = 32KB, same footprint),
// counted s_waitcnt vmcnt(4) prefetch across RAW s_barrier (T3/T4 minimum-2-phase) so
// tile kt+1's global->LDS latency hides under tile kt's compute. T5 setprio around MFMAs.
__global__ __launch_bounds__(256)
void flash_attn(const short* __restrict__ QKb, const short* __restrict__ Vt,
                short* __restrict__ Og)
{
    constexpr int L = 2048, LQ = 1280, HD = 64;
    constexpr int NT = L / 64;                               // 32 key-tiles of 64
    __shared__ __attribute__((aligned(16))) short smem[2 * 8192]; // [buf][Ks 4096 | Vs 4096]

    const int t = threadIdx.x, lane = t & 63, w = t >> 6;
    const int lr = lane & 15, quad = lane >> 4;
    const int qt = blockIdx.x, h = blockIdx.y, b = blockIdx.z;
    const int kh = h >> 2;
    const int q0 = qt * 128;
    const int kcol = 1024 + kh * HD;

    // Q B-frags (wave owns q-cols w*32..w*32+31 of S^T / O^T)
    sh8 qf[2][2];
#pragma unroll
    for (int nt = 0; nt < 2; ++nt)
#pragma unroll
        for (int ks = 0; ks < 2; ++ks)
            qf[nt][ks] = *reinterpret_cast<const sh8*>(
                QKb + (size_t)(b * L + q0 + w * 32 + nt * 16 + lr) * LQ + h * HD + ks * 32 + quad * 8);

    float l_st[2] = {};
    f4v oT[4][2] = {};

    const int r8 = lane >> 3, g8 = lane & 7;
    const short* Vbase = Vt + (size_t)kh * HD * 8192;

    // stage one 64-key tile: Ks (key-permuted, swizzle ^=(r&7)) + Vs (d-major, swizzle ^=(r&7))
    // 4 glds16 per thread per tile -> counted vmcnt
    auto stage = [&](int buf, int kt) {
        short* Ks = smem + buf * 8192;
        short* Vs = Ks + 4096;
        const int kv0 = b * L + kt * 64;
#pragma unroll
        for (int p = 0; p < 2; ++p) {
            const int s = 2 * w + p;
            const int r = s * 8 + r8;                         // perm-row 0..63
            const int mm = r & 15;
            const int key = ((r >> 5) << 5) + ((mm >> 2) << 3) + (((r >> 4) & 1) << 2) + (mm & 3);
            const int g = g8 ^ (r & 7);
            glds16(QKb + (size_t)(kv0 + key) * LQ + kcol + g * 8, &Ks[s * 512]);
        }
#pragma unroll
        for (int p = 0; p < 2; ++p) {
            const int s = 2 * w + p;
            const int r = s * 8 + r8;                         // d-row 0..63
            const int g = g8 ^ (r & 7);
            glds16(Vbase + (size_t)r * 8192 + kv0 + g * 8, &Vs[s * 512]);
        }
    };

    stage(0, 0);                                              // prologue prefetch

    for (int kt = 0; kt < NT; ++kt) {
        const int cur = kt & 1;
        if (kt + 1 < NT) {
            stage(cur ^ 1, kt + 1);                           // issue next tile early
            asm volatile("s_waitcnt vmcnt(4)" ::: "memory");  // current tile landed (4 newer in flight)
        } else {
            asm volatile("s_waitcnt vmcnt(0)" ::: "memory");
        }
        __builtin_amdgcn_s_barrier();                         // publish: all waves' tile kt ready
        asm volatile("" ::: "memory");                        // no ds_read hoisting above barrier

        const short* Ks = smem + cur * 8192;
        const short* Vs = Ks + 4096;

        // S^T = K·Q^T for 64 keys
        f4v st[4][2] = {};
        __builtin_amdgcn_s_setprio(1);
#pragma unroll
        for (int nl = 0; nl < 4; ++nl) {
            const int R = nl * 16 + lr;
            const int f = lr & 7;
            sh8 a0 = *reinterpret_cast<const sh8*>(&Ks[R * 64 + ((quad ^ f) << 3)]);
            sh8 a1 = *reinterpret_cast<const sh8*>(&Ks[R * 64 + (((4 + quad) ^ f) << 3)]);
#pragma unroll
            for (int nt = 0; nt < 2; ++nt) {
                st[nl][nt] = __builtin_amdgcn_mfma_f32_16x16x32_bf16(a0, qf[nt][0], st[nl][nt], 0, 0, 0);
                st[nl][nt] = __builtin_amdgcn_mfma_f32_16x16x32_bf16(a1, qf[nt][1], st[nl][nt], 0, 0, 0);
            }
        }
        __builtin_amdgcn_s_setprio(0);

        // exp2 -> P^T B-frags in registers -> PV MFMA
#pragma unroll
        for (int cl = 0; cl < 2; ++cl) {
            sh8 vf[4];
#pragma unroll
            for (int m = 0; m < 4; ++m)
                vf[m] = *reinterpret_cast<const sh8*>(
                    &Vs[(16 * m + lr) * 64 + (((cl * 4 + quad) ^ (lr & 7)) << 3)]);
#pragma unroll
            for (int nt = 0; nt < 2; ++nt) {
                f4v e0, e1;
#pragma unroll
                for (int i = 0; i < 4; ++i) {
                    e0[i] = EXP2(st[2 * cl][nt][i]);
                    e1[i] = EXP2(st[2 * cl + 1][nt][i]);
                }
                l_st[nt] += (e0[0] + e0[1]) + (e0[2] + e0[3]) +
                            (e1[0] + e1[1]) + (e1[2] + e1[3]);
                u4v pu = { pk_bf16(e0[0], e0[1]), pk_bf16(e0[2], e0[3]),
                           pk_bf16(e1[0], e1[1]), pk_bf16(e1[2], e1[3]) };
                sh8 pf = __builtin_bit_cast(sh8, pu);
                __builtin_amdgcn_s_setprio(1);
#pragma unroll
                for (int m = 0; m < 4; ++m)
                    oT[m][nt] = __builtin_amdgcn_mfma_f32_16x16x32_bf16(vf[m], pf, oT[m][nt], 0, 0, 0);
                __builtin_amdgcn_s_setprio(0);
            }
        }

        asm volatile("" ::: "memory");                        // reads done before release
        __builtin_amdgcn_s_barrier();                         // release: buf[cur^1] may be overwritten
        asm volatile("" ::: "memory");                        // next stage stays below barrier
    }

    // normalize + store O^T -> Og[token][h*64+d]
#pragma unroll
    for (int nt = 0; nt < 2; ++nt) {
        float l = l_st[nt];
        l += __shfl_xor(l, 16, 64);
        l += __shfl_xor(l, 32, 64);
        const float inv = 1.0f / l;
        const size_t tok = (size_t)b * L + q0 + w * 32 + nt * 16 + lr;
        short* op = Og + tok * 1024 + h * HD + quad * 4;
#pragma unroll
        for (int m = 0; m < 4; ++m) {
            u2v pk2 = { pk_bf16(oT[m][nt][0] * inv, oT[m][nt][1] * inv),
                        pk_bf16(oT[m][nt][2] * inv, oT[m][nt][3] * inv) };
            *reinterpret_cast<u2v*>(op + m * 16) = pk2;
        }
    }
}

extern "C" void kernel_launch(void* const* d_in, const int* in_sizes, int n_in,
                              void* d_out, int out_size, void* d_ws, size_t ws_size,
                              hipStream_t stream)
{
    (void)in_sizes; (void)n_in; (void)out_size; (void)ws_size;
    const float* x  = (const float*)d_in[0];
    const float* Wq = (const float*)d_in[1];
    const float* bq = (const float*)d_in[2];
    const float* Wk = (const float*)d_in[3];
    const float* bk = (const float*)d_in[4];
    const float* Wv = (const float*)d_in[5];
    const float* bv = (const float*)d_in[6];
    const float* Wo = (const float*)d_in[7];
    const float* bo = (const float*)d_in[8];
    float* out = (float*)d_out;

    char* ws = (char*)d_ws;
    short* xb   = (short*)(ws);                     // 8192x1024 bf16 = 16 MB
    short* Ob   = (short*)(ws);                     // aliases xb (dead after proj)
    short* Wqkb = (short*)(ws + 16777216);          // 1280x1024 bf16 = 2.5 MB
    short* Wvb  = (short*)(ws + 19398656);          // 256x1024 bf16 = 512 KB
    short* Wob  = (short*)(ws + 19922944);          // 1024x1024 bf16 = 2 MB
    float* bqk  = (float*)(ws + 22020096);          // 1280 fp32
    float* bvf  = (float*)(ws + 22025216);          // 256 fp32
    short* Vt   = (short*)(ws + 25165824);          // 256x8192 bf16 = 4 MB (V^T)
    short* QKb  = (short*)d_out;                    // 8192x1280 bf16 = 20 MB scratch

    pack_all<<<10754, 256, 0, stream>>>(x, Wq, Wk, Wv, Wo, bq, bk, bv,
                                        xb, Wqkb, Wvb, Wob, bqk, bvf);
    proj_fused<<<768, 256, 0, stream>>>(xb, Wqkb, bqk, QKb, Wvb, bvf, Vt);
    flash_attn<<<dim3(16, 16, 4), 256, 0, stream>>>(QKb, Vt, Ob);
    gemm_out<<<dim3(8, 64), 256, 0, stream>>>(Ob, Wob, bo, out, 8192, 1024, 1024);
}

// Round 2
// 252.119 us; speedup vs baseline: 1.0983x; 1.0500x over previous
//
#include <hip/hip_runtime.h>
#include <hip/hip_bf16.h>

typedef __attribute__((ext_vector_type(8))) short sh8;
typedef __attribute__((ext_vector_type(4))) short sh4;
typedef __attribute__((ext_vector_type(4))) float f4v;
typedef __attribute__((ext_vector_type(4))) unsigned u4v;
typedef __attribute__((ext_vector_type(2))) unsigned u2v;

#define SCALE_Q 0.1803368801f   // 0.125 * log2(e): folds softmax scale AND exp->exp2

__device__ __forceinline__ short f2bf(float f) {
    unsigned u = __builtin_bit_cast(unsigned, f);
    u += 0x7fffu + ((u >> 16) & 1u);   // RNE
    return (short)(u >> 16);
}

#if __has_builtin(__builtin_amdgcn_cvt_pk_bf16_f32)
__device__ __forceinline__ unsigned pk_bf16(float a, float b) {
    return __builtin_bit_cast(unsigned, __builtin_amdgcn_cvt_pk_bf16_f32(a, b));
}
#else
__device__ __forceinline__ unsigned pk_bf16(float a, float b) {
    return (unsigned)(unsigned short)f2bf(a) | ((unsigned)(unsigned short)f2bf(b) << 16);
}
#endif

#if __has_builtin(__builtin_amdgcn_exp2f)
#define EXP2(x) __builtin_amdgcn_exp2f(x)
#else
#define EXP2(x) exp2f(x)
#endif

__device__ __forceinline__ void glds16(const short* g, short* l) {
    __builtin_amdgcn_global_load_lds(
        (const __attribute__((address_space(1))) void*)g,
        (__attribute__((address_space(3))) void*)l, 16, 0, 0);
}

// ---------------- pack: fp32 -> bf16 conversions + weight fusion ----------------
// vec4 regions: x->xb | Wq->Wqkb(scaled) | Wk->Wqkb+1M | Wv->Wvb | Wo->Wob | biases
__global__ __launch_bounds__(256)
void pack_all(const float* __restrict__ x,  const float* __restrict__ Wq,
              const float* __restrict__ Wk, const float* __restrict__ Wv,
              const float* __restrict__ Wo, const float* __restrict__ bq,
              const float* __restrict__ bk, const float* __restrict__ bv,
              short* __restrict__ xb, short* __restrict__ Wqkb,
              short* __restrict__ Wvb, short* __restrict__ Wob,
              float* __restrict__ bqk, float* __restrict__ bvf)
{
    const long idx = (long)blockIdx.x * 256 + threadIdx.x;
    if (idx >= 2752896) return;
    const float* src; short* dst; float sc = 1.0f; long off;
    if (idx < 2097152)       { off = idx;           src = x;  dst = xb; }
    else if (idx < 2359296)  { off = idx - 2097152; src = Wq; dst = Wqkb;           sc = SCALE_Q; }
    else if (idx < 2424832)  { off = idx - 2359296; src = Wk; dst = Wqkb + 1048576; }
    else if (idx < 2490368)  { off = idx - 2424832; src = Wv; dst = Wvb; }
    else if (idx < 2752512)  { off = idx - 2490368; src = Wo; dst = Wob; }
    else {
        long j = idx - 2752512;  // 0..383
        const float* bs; float* bd; float s2 = 1.0f;
        if (j < 256)      { bs = bq + j * 4;         bd = bqk + j * 4;          s2 = SCALE_Q; }
        else if (j < 320) { bs = bk + (j - 256) * 4; bd = bqk + 1024 + (j - 256) * 4; }
        else              { bs = bv + (j - 320) * 4; bd = bvf + (j - 320) * 4; }
        f4v v = *reinterpret_cast<const f4v*>(bs);
        f4v o = { v[0] * s2, v[1] * s2, v[2] * s2, v[3] * s2 };
        *reinterpret_cast<f4v*>(bd) = o;
        return;
    }
    f4v v = *reinterpret_cast<const f4v*>(src + off * 4);
    sh4 o; o[0] = f2bf(v[0] * sc); o[1] = f2bf(v[1] * sc);
    o[2] = f2bf(v[2] * sc); o[3] = f2bf(v[3] * sc);
    *reinterpret_cast<sh4*>(dst + off * 4) = o;
}

// ---------------- fused projection: QK GEMM + V-transposed GEMM, one grid ----------------
// Blocks 0..639:   QKb[8192][1280] = xb[8192][1024] · Wqkb[1280][1024]^T + bqk (col bias)
// Blocks 640..767: Vt [256][8192]  = Wvb[256][1024] · xb[8192][1024]^T  + bvf (row bias)
//   (swapped operands make the token axis the store-lane axis -> coalesced Vt, no scatter)
// Grid 768 = 3 x 256: zero tail. K=1024, 128x128 tiles, m97-style glds staging.
__global__ __launch_bounds__(256)
void proj_fused(const short* __restrict__ xb, const short* __restrict__ Wqkb,
                const float* __restrict__ bqk, short* __restrict__ QKb,
                const short* __restrict__ Wvb, const float* __restrict__ bvf,
                short* __restrict__ Vt)
{
    constexpr int K = 1024;
    __shared__ __attribute__((aligned(16))) short As[128 * 32];
    __shared__ __attribute__((aligned(16))) short Bs[128 * 32];

    const int t = threadIdx.x, lane = t & 63, w = t >> 6;
    const int lr = lane & 15, quad = lane >> 4;
    const int wm = (w >> 1) * 64, wn = (w & 1) * 64;
    const int sr = lane >> 2, sc = lane & 3;

    const int id = blockIdx.x;
    const short *A, *B; const float* bias; short* C;
    int m0, n0, N; bool brow;
    if (id < 640) {
        A = xb;  B = Wqkb; bias = bqk; C = QKb; N = 1280;
        m0 = (id / 10) * 128; n0 = (id % 10) * 128; brow = false;
    } else {
        const int v = id - 640;
        A = Wvb; B = xb;   bias = bvf; C = Vt;  N = 8192;
        m0 = (v >> 6) * 128; n0 = (v & 63) * 128; brow = true;
    }

    f4v acc[4][4] = {};

    for (int kb = 0; kb < K; kb += 32) {
#pragma unroll
        for (int p = 0; p < 2; ++p) {
            const int s = 2 * w + p;
            const int r = s * 16 + sr;
            const int g = sc ^ ((r >> 1) & 3);
            glds16(A + (size_t)(m0 + r) * K + kb + g * 8, &As[s * 512]);
            glds16(B + (size_t)(n0 + r) * K + kb + g * 8, &Bs[s * 512]);
        }
        __syncthreads();
        sh8 af[4], bfr[4];
#pragma unroll
        for (int i = 0; i < 4; ++i) {
            const int ra = wm + i * 16 + lr;
            af[i] = *reinterpret_cast<const sh8*>(&As[ra * 32 + ((quad ^ ((ra >> 1) & 3)) << 3)]);
            const int rb = wn + i * 16 + lr;
            bfr[i] = *reinterpret_cast<const sh8*>(&Bs[rb * 32 + ((quad ^ ((rb >> 1) & 3)) << 3)]);
        }
#pragma unroll
        for (int mi = 0; mi < 4; ++mi)
#pragma unroll
            for (int ni = 0; ni < 4; ++ni)
                acc[mi][ni] = __builtin_amdgcn_mfma_f32_16x16x32_bf16(af[mi], bfr[ni], acc[mi][ni], 0, 0, 0);
        __syncthreads();
    }

#pragma unroll
    for (int mi = 0; mi < 4; ++mi) {
        const int row = m0 + wm + mi * 16 + quad * 4;
        f4v br4 = {};
        if (brow) br4 = *reinterpret_cast<const f4v*>(&bias[row]);
#pragma unroll
        for (int ni = 0; ni < 4; ++ni) {
            const int col = n0 + wn + ni * 16 + lr;
            const float bc = brow ? 0.f : bias[col];
#pragma unroll
            for (int i = 0; i < 4; ++i) {
                const float v = acc[mi][ni][i] + (brow ? br4[i] : bc);
                C[(size_t)(row + i) * N + col] = f2bf(v);
            }
        }
    }
}

// ---------------- O-projection GEMM: out[M,N] = A[M,K] · W[N,K]^T + bias (fp32 out) ----------------
__global__ __launch_bounds__(256)
void gemm_out(const short* __restrict__ A, const short* __restrict__ B,
              const float* __restrict__ bias, float* __restrict__ Cv,
              int M, int N, int K)
{
    __shared__ __attribute__((aligned(16))) short As[128 * 32];
    __shared__ __attribute__((aligned(16))) short Bs[128 * 32];

    const int t = threadIdx.x, lane = t & 63, w = t >> 6;
    const int lr = lane & 15, quad = lane >> 4;
    const int m0 = blockIdx.y * 128, n0 = blockIdx.x * 128;
    const int wm = (w >> 1) * 64, wn = (w & 1) * 64;
    const int sr = lane >> 2, sc = lane & 3;

    f4v acc[4][4] = {};

    for (int kb = 0; kb < K; kb += 32) {
#pragma unroll
        for (int p = 0; p < 2; ++p) {
            const int s = 2 * w + p;
            const int r = s * 16 + sr;
            const int g = sc ^ ((r >> 1) & 3);
            glds16(A + (size_t)(m0 + r) * K + kb + g * 8, &As[s * 512]);
            glds16(B + (size_t)(n0 + r) * K + kb + g * 8, &Bs[s * 512]);
        }
        __syncthreads();
        sh8 af[4], bfr[4];
#pragma unroll
        for (int i = 0; i < 4; ++i) {
            const int ra = wm + i * 16 + lr;
            af[i] = *reinterpret_cast<const sh8*>(&As[ra * 32 + ((quad ^ ((ra >> 1) & 3)) << 3)]);
            const int rb = wn + i * 16 + lr;
            bfr[i] = *reinterpret_cast<const sh8*>(&Bs[rb * 32 + ((quad ^ ((rb >> 1) & 3)) << 3)]);
        }
#pragma unroll
        for (int mi = 0; mi < 4; ++mi)
#pragma unroll
            for (int ni = 0; ni < 4; ++ni)
                acc[mi][ni] = __builtin_amdgcn_mfma_f32_16x16x32_bf16(af[mi], bfr[ni], acc[mi][ni], 0, 0, 0);
        __syncthreads();
    }

#pragma unroll
    for (int ni = 0; ni < 4; ++ni) {
        const int col = n0 + wn + ni * 16 + lr;
        const float bv = bias[col];
#pragma unroll
        for (int mi = 0; mi < 4; ++mi) {
            const int row = m0 + wm + mi * 16 + quad * 4;
#pragma unroll
            for (int i = 0; i < 4; ++i)
                Cv[(size_t)(row + i) * N + col] = acc[mi][ni][i] + bv;
        }
    }
}

// ---------------- flash attention: S^T/O^T formulation, P in registers ----------------
// QKb [8192][1280]: Q cols 0..1023 (pre-scaled by 0.125*log2e), K cols 1024..1279.
// Vt [256][8192]: V^T, token-contiguous rows.
// NEW (this round): 512-thread / 8-wave blocks, each wave owns 16 q-cols (was 32).
// Same total MFMA/exp2 work spread over 2x the waves: targets the 19% occupancy
// (latency-bound) diagnosis. Keeps 64-key dbuf tiles + counted vmcnt(2) prefetch.
__global__ __launch_bounds__(512)
void flash_attn(const short* __restrict__ QKb, const short* __restrict__ Vt,
                short* __restrict__ Og)
{
    constexpr int L = 2048, LQ = 1280, HD = 64;
    constexpr int NT = L / 64;                               // 32 key-tiles of 64
    __shared__ __attribute__((aligned(16))) short smem[2 * 8192]; // [buf][Ks 4096sh | Vs 4096sh]

    const int t = threadIdx.x, lane = t & 63, w = t >> 6;    // w = 0..7
    const int lr = lane & 15, quad = lane >> 4;
    const int qt = blockIdx.x, h = blockIdx.y, b = blockIdx.z;
    const int kh = h >> 2;
    const int q0 = qt * 128;
    const int kcol = 1024 + kh * HD;

    // Q B-frags (wave owns q-cols w*16..w*16+15 of S^T / O^T)
    sh8 qf[2];
#pragma unroll
    for (int ks = 0; ks < 2; ++ks)
        qf[ks] = *reinterpret_cast<const sh8*>(
            QKb + (size_t)(b * L + q0 + w * 16 + lr) * LQ + h * HD + ks * 32 + quad * 8);

    float l_st = 0.f;
    f4v oT[4] = {};

    const int r8 = lane >> 3, g8 = lane & 7;
    const short* Vbase = Vt + (size_t)kh * HD * 8192;

    // stage one 64-key tile: wave w stages Ks segment w + Vs segment w (1 KB each)
    // -> 2 glds16 per wave per tile -> counted vmcnt(2)
    auto stage = [&](int buf, int kt) {
        short* Ks = smem + buf * 8192;
        short* Vs = Ks + 4096;
        const int kv0 = b * L + kt * 64;
        {
            const int r = w * 8 + r8;                         // perm-row 0..63
            const int mm = r & 15;
            const int key = ((r >> 5) << 5) + ((mm >> 2) << 3) + (((r >> 4) & 1) << 2) + (mm & 3);
            const int g = g8 ^ (r & 7);
            glds16(QKb + (size_t)(kv0 + key) * LQ + kcol + g * 8, &Ks[w * 512]);
        }
        {
            const int r = w * 8 + r8;                         // d-row 0..63
            const int g = g8 ^ (r & 7);
            glds16(Vbase + (size_t)r * 8192 + kv0 + g * 8, &Vs[w * 512]);
        }
    };

    stage(0, 0);                                              // prologue prefetch

    for (int kt = 0; kt < NT; ++kt) {
        const int cur = kt & 1;
        if (kt + 1 < NT) {
            stage(cur ^ 1, kt + 1);                           // issue next tile early
            asm volatile("s_waitcnt vmcnt(2)" ::: "memory");  // current tile landed (2 newer in flight)
        } else {
            asm volatile("s_waitcnt vmcnt(0)" ::: "memory");
        }
        __builtin_amdgcn_s_barrier();                         // publish: all waves' tile kt ready
        asm volatile("" ::: "memory");                        // no ds_read hoisting above barrier

        const short* Ks = smem + cur * 8192;
        const short* Vs = Ks + 4096;

        // S^T = K·Q^T for 64 keys x 16 q-cols
        f4v st[4] = {};
        __builtin_amdgcn_s_setprio(1);
#pragma unroll
        for (int nl = 0; nl < 4; ++nl) {
            const int R = nl * 16 + lr;
            const int f = lr & 7;
            sh8 a0 = *reinterpret_cast<const sh8*>(&Ks[R * 64 + ((quad ^ f) << 3)]);
            sh8 a1 = *reinterpret_cast<const sh8*>(&Ks[R * 64 + (((4 + quad) ^ f) << 3)]);
            st[nl] = __builtin_amdgcn_mfma_f32_16x16x32_bf16(a0, qf[0], st[nl], 0, 0, 0);
            st[nl] = __builtin_amdgcn_mfma_f32_16x16x32_bf16(a1, qf[1], st[nl], 0, 0, 0);
        }
        __builtin_amdgcn_s_setprio(0);

        // exp2 -> P^T B-frags in registers -> PV MFMA
#pragma unroll
        for (int cl = 0; cl < 2; ++cl) {
            sh8 vf[4];
#pragma unroll
            for (int m = 0; m < 4; ++m)
                vf[m] = *reinterpret_cast<const sh8*>(
                    &Vs[(16 * m + lr) * 64 + (((cl * 4 + quad) ^ (lr & 7)) << 3)]);
            f4v e0, e1;
#pragma unroll
            for (int i = 0; i < 4; ++i) {
                e0[i] = EXP2(st[2 * cl][i]);
                e1[i] = EXP2(st[2 * cl + 1][i]);
            }
            l_st += (e0[0] + e0[1]) + (e0[2] + e0[3]) +
                    (e1[0] + e1[1]) + (e1[2] + e1[3]);
            u4v pu = { pk_bf16(e0[0], e0[1]), pk_bf16(e0[2], e0[3]),
                       pk_bf16(e1[0], e1[1]), pk_bf16(e1[2], e1[3]) };
            sh8 pf = __builtin_bit_cast(sh8, pu);
            __builtin_amdgcn_s_setprio(1);
#pragma unroll
            for (int m = 0; m < 4; ++m)
                oT[m] = __builtin_amdgcn_mfma_f32_16x16x32_bf16(vf[m], pf, oT[m], 0, 0, 0);
            __builtin_amdgcn_s_setprio(0);
        }

        asm volatile("" ::: "memory");                        // reads done before release
        __builtin_amdgcn_s_barrier();                         // release: buf[cur^1] may be overwritten
        asm volatile("" ::: "memory");                        // next stage stays below barrier
    }

    // normalize + store O^T -> Og[token][h*64+d]
    {
        float l = l_st;
        l += __shfl_xor(l, 16, 64);
        l += __shfl_xor(l, 32, 64);
        const float inv = 1.0f / l;
        const size_t tok = (size_t)b * L + q0 + w * 16 + lr;
        short* op = Og + tok * 1024 + h * HD + quad * 4;
#pragma unroll
        for (int m = 0; m < 4; ++m) {
            u2v pk2 = { pk_bf16(oT[m][0] * inv, oT[m][1] * inv),
                        pk_bf16(oT[m][2] * inv, oT[m][3] * inv) };
            *reinterpret_cast<u2v*>(op + m * 16) = pk2;
        }
    }
}

extern "C" void kernel_launch(void* const* d_in, const int* in_sizes, int n_in,
                              void* d_out, int out_size, void* d_ws, size_t ws_size,
                              hipStream_t stream)
{
    (void)in_sizes; (void)n_in; (void)out_size; (void)ws_size;
    const float* x  = (const float*)d_in[0];
    const float* Wq = (const float*)d_in[1];
    const float* bq = (const float*)d_in[2];
    const float* Wk = (const float*)d_in[3];
    const float* bk = (const float*)d_in[4];
    const float* Wv = (const float*)d_in[5];
    const float* bv = (const float*)d_in[6];
    const float* Wo = (const float*)d_in[7];
    const float* bo = (const float*)d_in[8];
    float* out = (float*)d_out;

    char* ws = (char*)d_ws;
    short* xb   = (short*)(ws);                     // 8192x1024 bf16 = 16 MB
    short* Ob   = (short*)(ws);                     // aliases xb (dead after proj)
    short* Wqkb = (short*)(ws + 16777216);          // 1280x1024 bf16 = 2.5 MB
    short* Wvb  = (short*)(ws + 19398656);          // 256x1024 bf16 = 512 KB
    short* Wob  = (short*)(ws + 19922944);          // 1024x1024 bf16 = 2 MB
    float* bqk  = (float*)(ws + 22020096);          // 1280 fp32
    float* bvf  = (float*)(ws + 22025216);          // 256 fp32
    short* Vt   = (short*)(ws + 25165824);          // 256x8192 bf16 = 4 MB (V^T)
    short* QKb  = (short*)d_out;                    // 8192x1280 bf16 = 20 MB scratch

    pack_all<<<10754, 256, 0, stream>>>(x, Wq, Wk, Wv, Wo, bq, bk, bv,
                                        xb, Wqkb, Wvb, Wob, bqk, bvf);
    proj_fused<<<768, 256, 0, stream>>>(xb, Wqkb, bqk, QKb, Wvb, bvf, Vt);
    flash_attn<<<dim3(16, 16, 4), 512, 0, stream>>>(QKb, Vt, Ob);
    gemm_out<<<dim3(8, 64), 256, 0, stream>>>(Ob, Wob, bo, out, 8192, 1024, 1024);
}

// Round 3
// 246.974 us; speedup vs baseline: 1.1212x; 1.0208x over previous
//
#include <hip/hip_runtime.h>
#include <hip/hip_bf16.h>

typedef __attribute__((ext_vector_type(8))) short sh8;
typedef __attribute__((ext_vector_type(4))) short sh4;
typedef __attribute__((ext_vector_type(4))) float f4v;
typedef __attribute__((ext_vector_type(4))) unsigned u4v;
typedef __attribute__((ext_vector_type(2))) unsigned u2v;

#define SCALE_Q 0.1803368801f   // 0.125 * log2(e): folds softmax scale AND exp->exp2

__device__ __forceinline__ short f2bf(float f) {
    unsigned u = __builtin_bit_cast(unsigned, f);
    u += 0x7fffu + ((u >> 16) & 1u);   // RNE
    return (short)(u >> 16);
}

#if __has_builtin(__builtin_amdgcn_cvt_pk_bf16_f32)
__device__ __forceinline__ unsigned pk_bf16(float a, float b) {
    return __builtin_bit_cast(unsigned, __builtin_amdgcn_cvt_pk_bf16_f32(a, b));
}
#else
__device__ __forceinline__ unsigned pk_bf16(float a, float b) {
    return (unsigned)(unsigned short)f2bf(a) | ((unsigned)(unsigned short)f2bf(b) << 16);
}
#endif

#if __has_builtin(__builtin_amdgcn_exp2f)
#define EXP2(x) __builtin_amdgcn_exp2f(x)
#else
#define EXP2(x) exp2f(x)
#endif

__device__ __forceinline__ void glds16(const short* g, short* l) {
    __builtin_amdgcn_global_load_lds(
        (const __attribute__((address_space(1))) void*)g,
        (__attribute__((address_space(3))) void*)l, 16, 0, 0);
}

// ---------------- pack: fp32 -> bf16 conversions + weight fusion ----------------
// vec4 regions: x->xb | Wq->Wqkb(scaled) | Wk->Wqkb+1M | Wv->Wvb | Wo->Wob | biases
__global__ __launch_bounds__(256)
void pack_all(const float* __restrict__ x,  const float* __restrict__ Wq,
              const float* __restrict__ Wk, const float* __restrict__ Wv,
              const float* __restrict__ Wo, const float* __restrict__ bq,
              const float* __restrict__ bk, const float* __restrict__ bv,
              short* __restrict__ xb, short* __restrict__ Wqkb,
              short* __restrict__ Wvb, short* __restrict__ Wob,
              float* __restrict__ bqk, float* __restrict__ bvf)
{
    const long idx = (long)blockIdx.x * 256 + threadIdx.x;
    if (idx >= 2752896) return;
    const float* src; short* dst; float sc = 1.0f; long off;
    if (idx < 2097152)       { off = idx;           src = x;  dst = xb; }
    else if (idx < 2359296)  { off = idx - 2097152; src = Wq; dst = Wqkb;           sc = SCALE_Q; }
    else if (idx < 2424832)  { off = idx - 2359296; src = Wk; dst = Wqkb + 1048576; }
    else if (idx < 2490368)  { off = idx - 2424832; src = Wv; dst = Wvb; }
    else if (idx < 2752512)  { off = idx - 2490368; src = Wo; dst = Wob; }
    else {
        long j = idx - 2752512;  // 0..383
        const float* bs; float* bd; float s2 = 1.0f;
        if (j < 256)      { bs = bq + j * 4;         bd = bqk + j * 4;          s2 = SCALE_Q; }
        else if (j < 320) { bs = bk + (j - 256) * 4; bd = bqk + 1024 + (j - 256) * 4; }
        else              { bs = bv + (j - 320) * 4; bd = bvf + (j - 320) * 4; }
        f4v v = *reinterpret_cast<const f4v*>(bs);
        f4v o = { v[0] * s2, v[1] * s2, v[2] * s2, v[3] * s2 };
        *reinterpret_cast<f4v*>(bd) = o;
        return;
    }
    f4v v = *reinterpret_cast<const f4v*>(src + off * 4);
    sh4 o; o[0] = f2bf(v[0] * sc); o[1] = f2bf(v[1] * sc);
    o[2] = f2bf(v[2] * sc); o[3] = f2bf(v[3] * sc);
    *reinterpret_cast<sh4*>(dst + off * 4) = o;
}

// ---------------- fused projection: QK GEMM + V-transposed GEMM, one grid ----------------
// Blocks 0..639:   QKb[8192][1280] = xb[8192][1024] · Wqkb[1280][1024]^T + bqk (col bias)
// Blocks 640..767: Vt [256][8192]  = Wvb[256][1024] · xb[8192][1024]^T  + bvf (row bias)
//   (swapped operands make the token axis the store-lane axis -> coalesced Vt, no scatter)
// Grid 768 = 3 x 256: zero tail. K=1024, 128x128 tiles, m97-style glds staging.
__global__ __launch_bounds__(256)
void proj_fused(const short* __restrict__ xb, const short* __restrict__ Wqkb,
                const float* __restrict__ bqk, short* __restrict__ QKb,
                const short* __restrict__ Wvb, const float* __restrict__ bvf,
                short* __restrict__ Vt)
{
    constexpr int K = 1024;
    __shared__ __attribute__((aligned(16))) short As[128 * 32];
    __shared__ __attribute__((aligned(16))) short Bs[128 * 32];

    const int t = threadIdx.x, lane = t & 63, w = t >> 6;
    const int lr = lane & 15, quad = lane >> 4;
    const int wm = (w >> 1) * 64, wn = (w & 1) * 64;
    const int sr = lane >> 2, sc = lane & 3;

    const int id = blockIdx.x;
    const short *A, *B; const float* bias; short* C;
    int m0, n0, N; bool brow;
    if (id < 640) {
        A = xb;  B = Wqkb; bias = bqk; C = QKb; N = 1280;
        m0 = (id / 10) * 128; n0 = (id % 10) * 128; brow = false;
    } else {
        const int v = id - 640;
        A = Wvb; B = xb;   bias = bvf; C = Vt;  N = 8192;
        m0 = (v >> 6) * 128; n0 = (v & 63) * 128; brow = true;
    }

    f4v acc[4][4] = {};

    for (int kb = 0; kb < K; kb += 32) {
#pragma unroll
        for (int p = 0; p < 2; ++p) {
            const int s = 2 * w + p;
            const int r = s * 16 + sr;
            const int g = sc ^ ((r >> 1) & 3);
            glds16(A + (size_t)(m0 + r) * K + kb + g * 8, &As[s * 512]);
            glds16(B + (size_t)(n0 + r) * K + kb + g * 8, &Bs[s * 512]);
        }
        __syncthreads();
        sh8 af[4], bfr[4];
#pragma unroll
        for (int i = 0; i < 4; ++i) {
            const int ra = wm + i * 16 + lr;
            af[i] = *reinterpret_cast<const sh8*>(&As[ra * 32 + ((quad ^ ((ra >> 1) & 3)) << 3)]);
            const int rb = wn + i * 16 + lr;
            bfr[i] = *reinterpret_cast<const sh8*>(&Bs[rb * 32 + ((quad ^ ((rb >> 1) & 3)) << 3)]);
        }
#pragma unroll
        for (int mi = 0; mi < 4; ++mi)
#pragma unroll
            for (int ni = 0; ni < 4; ++ni)
                acc[mi][ni] = __builtin_amdgcn_mfma_f32_16x16x32_bf16(af[mi], bfr[ni], acc[mi][ni], 0, 0, 0);
        __syncthreads();
    }

#pragma unroll
    for (int mi = 0; mi < 4; ++mi) {
        const int row = m0 + wm + mi * 16 + quad * 4;
        f4v br4 = {};
        if (brow) br4 = *reinterpret_cast<const f4v*>(&bias[row]);
#pragma unroll
        for (int ni = 0; ni < 4; ++ni) {
            const int col = n0 + wn + ni * 16 + lr;
            const float bc = brow ? 0.f : bias[col];
#pragma unroll
            for (int i = 0; i < 4; ++i) {
                const float v = acc[mi][ni][i] + (brow ? br4[i] : bc);
                C[(size_t)(row + i) * N + col] = f2bf(v);
            }
        }
    }
}

// ---------------- O-projection GEMM: out[M,N] = A[M,K] · W[N,K]^T + bias (fp32 out) ----------------
__global__ __launch_bounds__(256)
void gemm_out(const short* __restrict__ A, const short* __restrict__ B,
              const float* __restrict__ bias, float* __restrict__ Cv,
              int M, int N, int K)
{
    __shared__ __attribute__((aligned(16))) short As[128 * 32];
    __shared__ __attribute__((aligned(16))) short Bs[128 * 32];

    const int t = threadIdx.x, lane = t & 63, w = t >> 6;
    const int lr = lane & 15, quad = lane >> 4;
    const int m0 = blockIdx.y * 128, n0 = blockIdx.x * 128;
    const int wm = (w >> 1) * 64, wn = (w & 1) * 64;
    const int sr = lane >> 2, sc = lane & 3;

    f4v acc[4][4] = {};

    for (int kb = 0; kb < K; kb += 32) {
#pragma unroll
        for (int p = 0; p < 2; ++p) {
            const int s = 2 * w + p;
            const int r = s * 16 + sr;
            const int g = sc ^ ((r >> 1) & 3);
            glds16(A + (size_t)(m0 + r) * K + kb + g * 8, &As[s * 512]);
            glds16(B + (size_t)(n0 + r) * K + kb + g * 8, &Bs[s * 512]);
        }
        __syncthreads();
        sh8 af[4], bfr[4];
#pragma unroll
        for (int i = 0; i < 4; ++i) {
            const int ra = wm + i * 16 + lr;
            af[i] = *reinterpret_cast<const sh8*>(&As[ra * 32 + ((quad ^ ((ra >> 1) & 3)) << 3)]);
            const int rb = wn + i * 16 + lr;
            bfr[i] = *reinterpret_cast<const sh8*>(&Bs[rb * 32 + ((quad ^ ((rb >> 1) & 3)) << 3)]);
        }
#pragma unroll
        for (int mi = 0; mi < 4; ++mi)
#pragma unroll
            for (int ni = 0; ni < 4; ++ni)
                acc[mi][ni] = __builtin_amdgcn_mfma_f32_16x16x32_bf16(af[mi], bfr[ni], acc[mi][ni], 0, 0, 0);
        __syncthreads();
    }

#pragma unroll
    for (int ni = 0; ni < 4; ++ni) {
        const int col = n0 + wn + ni * 16 + lr;
        const float bv = bias[col];
#pragma unroll
        for (int mi = 0; mi < 4; ++mi) {
            const int row = m0 + wm + mi * 16 + quad * 4;
#pragma unroll
            for (int i = 0; i < 4; ++i)
                Cv[(size_t)(row + i) * N + col] = acc[mi][ni][i] + bv;
        }
    }
}

// ---------------- flash attention: S^T/O^T formulation, P in registers ----------------
// QKb [8192][1280]: Q cols 0..1023 (pre-scaled by 0.125*log2e), K cols 1024..1279.
// Vt [256][8192]: V^T, token-contiguous rows.
// R2 result: VALU-issue-bound (VALUBusy 64 + MfmaUtil 32 = 96%). This round cuts
// per-tile VALU overhead: 128-key tiles (16 iters, half the fixed cost), unroll-by-2
// for compile-time dbuf offsets (ds_read addrs become base+immediate), carried
// staging pointers (no per-tile 64-bit addr rebuild), and l-sum via MFMA ones-row
// (kills 28 adds/tile + the final cross-lane shuffles). 8 waves, 64 KB LDS,
// still 2 blocks/CU. Counted vmcnt(4) prefetch across raw barriers.
__global__ __launch_bounds__(512)
void flash_attn(const short* __restrict__ QKb, const short* __restrict__ Vt,
                short* __restrict__ Og)
{
    constexpr int L = 2048, LQ = 1280, HD = 64;
    constexpr int NT = L / 128;                              // 16 key-tiles of 128
    __shared__ __attribute__((aligned(16))) short smem[2 * 16384]; // 64 KB: [buf][Ks 8192 | Vs 8192]

    const int t = threadIdx.x, lane = t & 63, w = t >> 6;    // w = 0..7
    const int lr = lane & 15, quad = lane >> 4;
    const int qt = blockIdx.x, h = blockIdx.y, b = blockIdx.z;
    const int kh = h >> 2;
    const int q0 = qt * 128;
    const int kcol = 1024 + kh * HD;

    // Q B-frags (wave owns q-cols w*16..w*16+15 of S^T / O^T)
    sh8 qf[2];
#pragma unroll
    for (int ks = 0; ks < 2; ++ks)
        qf[ks] = *reinterpret_cast<const sh8*>(
            QKb + (size_t)(b * L + q0 + w * 16 + lr) * LQ + h * HD + ks * 32 + quad * 8);

    f4v oT[4] = {};
    f4v lacc = {};                                   // denominator via MFMA ones-row
    sh8 ones;
#pragma unroll
    for (int i = 0; i < 8; ++i) ones[i] = (short)0x3F80;   // bf16 1.0

    // staging pointers, advanced by fixed stride per tile (no per-tile addr rebuild)
    const int r8 = lane >> 3, g8 = lane & 7;        // K staging: row-in-seg, chunk
    const int v_r4 = lane >> 4, v_g = lane & 15;    // V staging: row-in-seg, chunk
    const short* Vbase = Vt + (size_t)kh * HD * 8192;
    const short* Kp[2];
    const short* Vp[2];
#pragma unroll
    for (int p = 0; p < 2; ++p) {
        const int s = 2 * w + p;
        const int rk = s * 8 + r8;                   // perm-row 0..127
        const int mm = rk & 15;
        const int key = ((rk >> 5) << 5) + ((mm >> 2) << 3) + (((rk >> 4) & 1) << 2) + (mm & 3);
        const int gk = g8 ^ (rk & 7);
        Kp[p] = QKb + (size_t)(b * L + key) * LQ + kcol + gk * 8;
        const int rv = s * 4 + v_r4;                 // d-row 0..63
        const int gv = v_g ^ (rv & 15);
        Vp[p] = Vbase + (size_t)rv * 8192 + b * L + gv * 8;
    }

    // stage one 128-key tile into buf: Ks [128 perm-rows][64 d] (swz ^(r&7)),
    // Vs [64 d][128 keys] (swz ^(r&15)). 4 glds16 per thread per tile.
    auto stage = [&](int buf) {
        short* Ks = smem + buf * 16384;
        short* Vs = Ks + 8192;
#pragma unroll
        for (int p = 0; p < 2; ++p) {
            glds16(Kp[p], &Ks[(2 * w + p) * 512]);
            glds16(Vp[p], &Vs[(2 * w + p) * 512]);
            Kp[p] += 128 * LQ;                       // next 128 keys (token rows)
            Vp[p] += 128;                            // next 128 keys (within V^T row)
        }
    };

    auto body = [&](int buf, int kt) {
        if (kt + 1 < NT) {
            stage(buf ^ 1);                          // issue next tile early
            asm volatile("s_waitcnt vmcnt(4)" ::: "memory");  // current tile landed
        } else {
            asm volatile("s_waitcnt vmcnt(0)" ::: "memory");
        }
        __builtin_amdgcn_s_barrier();                // publish: tile kt ready
        asm volatile("" ::: "memory");

        const short* Ks = smem + buf * 16384;        // buf is compile-time constant here
        const short* Vs = Ks + 8192;

#pragma unroll
        for (int half = 0; half < 2; ++half) {
            // S^T = K·Q^T for keys [half*64, half*64+64) x 16 q-cols
            f4v st[4] = {};
            __builtin_amdgcn_s_setprio(1);
#pragma unroll
            for (int nl = 0; nl < 4; ++nl) {
                const int R = (half * 4 + nl) * 16 + lr;
                const int f = lr & 7;
                sh8 a0 = *reinterpret_cast<const sh8*>(&Ks[R * 64 + ((quad ^ f) << 3)]);
                sh8 a1 = *reinterpret_cast<const sh8*>(&Ks[R * 64 + (((4 + quad) ^ f) << 3)]);
                st[nl] = __builtin_amdgcn_mfma_f32_16x16x32_bf16(a0, qf[0], st[nl], 0, 0, 0);
                st[nl] = __builtin_amdgcn_mfma_f32_16x16x32_bf16(a1, qf[1], st[nl], 0, 0, 0);
            }
            __builtin_amdgcn_s_setprio(0);

            // exp2 -> P^T B-frags in registers -> PV MFMA (+ l via ones-row MFMA)
#pragma unroll
            for (int cl = 0; cl < 2; ++cl) {
                const int c = half * 2 + cl;
                sh8 vf[4];
#pragma unroll
                for (int m = 0; m < 4; ++m)
                    vf[m] = *reinterpret_cast<const sh8*>(
                        &Vs[(16 * m + lr) * 128 + (((c * 4 + quad) ^ (lr & 15)) << 3)]);
                f4v e0, e1;
#pragma unroll
                for (int i = 0; i < 4; ++i) {
                    e0[i] = EXP2(st[2 * cl][i]);
                    e1[i] = EXP2(st[2 * cl + 1][i]);
                }
                u4v pu = { pk_bf16(e0[0], e0[1]), pk_bf16(e0[2], e0[3]),
                           pk_bf16(e1[0], e1[1]), pk_bf16(e1[2], e1[3]) };
                sh8 pf = __builtin_bit_cast(sh8, pu);
                __builtin_amdgcn_s_setprio(1);
                lacc = __builtin_amdgcn_mfma_f32_16x16x32_bf16(ones, pf, lacc, 0, 0, 0);
#pragma unroll
                for (int m = 0; m < 4; ++m)
                    oT[m] = __builtin_amdgcn_mfma_f32_16x16x32_bf16(vf[m], pf, oT[m], 0, 0, 0);
                __builtin_amdgcn_s_setprio(0);
            }
        }

        asm volatile("" ::: "memory");               // reads done before release
        __builtin_amdgcn_s_barrier();                // release: buf^1 may be overwritten
        asm volatile("" ::: "memory");
    };

    stage(0);                                        // prologue prefetch
#pragma unroll 1
    for (int kt = 0; kt < NT; kt += 2) {
        body(0, kt);
        body(1, kt + 1);
    }

    // normalize + store O^T -> Og[token][h*64+d].  l = lacc[i] (all rows identical).
    {
        const float inv = 1.0f / lacc[0];
        const size_t tok = (size_t)b * L + q0 + w * 16 + lr;
        short* op = Og + tok * 1024 + h * HD + quad * 4;
#pragma unroll
        for (int m = 0; m < 4; ++m) {
            u2v pk2 = { pk_bf16(oT[m][0] * inv, oT[m][1] * inv),
                        pk_bf16(oT[m][2] * inv, oT[m][3] * inv) };
            *reinterpret_cast<u2v*>(op + m * 16) = pk2;
        }
    }
}

extern "C" void kernel_launch(void* const* d_in, const int* in_sizes, int n_in,
                              void* d_out, int out_size, void* d_ws, size_t ws_size,
                              hipStream_t stream)
{
    (void)in_sizes; (void)n_in; (void)out_size; (void)ws_size;
    const float* x  = (const float*)d_in[0];
    const float* Wq = (const float*)d_in[1];
    const float* bq = (const float*)d_in[2];
    const float* Wk = (const float*)d_in[3];
    const float* bk = (const float*)d_in[4];
    const float* Wv = (const float*)d_in[5];
    const float* bv = (const float*)d_in[6];
    const float* Wo = (const float*)d_in[7];
    const float* bo = (const float*)d_in[8];
    float* out = (float*)d_out;

    char* ws = (char*)d_ws;
    short* xb   = (short*)(ws);                     // 8192x1024 bf16 = 16 MB
    short* Ob   = (short*)(ws);                     // aliases xb (dead after proj)
    short* Wqkb = (short*)(ws + 16777216);          // 1280x1024 bf16 = 2.5 MB
    short* Wvb  = (short*)(ws + 19398656);          // 256x1024 bf16 = 512 KB
    short* Wob  = (short*)(ws + 19922944);          // 1024x1024 bf16 = 2 MB
    float* bqk  = (float*)(ws + 22020096);          // 1280 fp32
    float* bvf  = (float*)(ws + 22025216);          // 256 fp32
    short* Vt   = (short*)(ws + 25165824);          // 256x8192 bf16 = 4 MB (V^T)
    short* QKb  = (short*)d_out;                    // 8192x1280 bf16 = 20 MB scratch

    pack_all<<<10754, 256, 0, stream>>>(x, Wq, Wk, Wv, Wo, bq, bk, bv,
                                        xb, Wqkb, Wvb, Wob, bqk, bvf);
    proj_fused<<<768, 256, 0, stream>>>(xb, Wqkb, bqk, QKb, Wvb, bvf, Vt);
    flash_attn<<<dim3(16, 16, 4), 512, 0, stream>>>(QKb, Vt, Ob);
    gemm_out<<<dim3(8, 64), 256, 0, stream>>>(Ob, Wob, bo, out, 8192, 1024, 1024);
}